// Round 10
// baseline (296.665 us; speedup 1.0000x reference)
//
#include <hip/hip_runtime.h>
#include <hip/hip_bf16.h>
#include <math.h>

#define D 2048
#define H 256
#define E 16
#define TMB 64                 // tokens per block
#define BK 16                  // k-chunk; each ku-lane owns a 4-k window
#define NCH (D / BK)           // 128
#define LDK 20                 // Wp LDS row stride (floats): (5tx+ku)&7 uniform bank groups
#define WP_OFF 0               // [256][20] = 5120 floats
#define X_OFF 5120             // [64][16]  = 1024  (staging ends 6144)
#define SB_LDW 257             // proj buffer stride: <=2-way conflicts on strided reads
#define SB_OFF 0               // [32][257] = 8224 (aliases staging during post)
#define WG_OFF 8224            // [16][256] = 4096 (persistent, staged at kernel start)
#define LB_OFF 12320
#define Z_OFF  12336
#define SMEM_FLOATS 12352      // 49.4 KB -> 1 block/CU
#define THREADS 1024
#define WS_STRIDE 20

// R8/R9 lesson: with 1024-thr workgroups the backend's default heuristic targets
// 32 waves/CU -> 64-VGPR cap -> catastrophic spill (WRITE_SIZE 86MB), and
// __launch_bounds__'s 2nd arg (a MINIMUM) cannot relax it. Pin occupancy to
// exactly 4 waves/EU (= our one 16-wave block) -> 128-VGPR budget.
__global__ __launch_bounds__(THREADS)
__attribute__((amdgpu_waves_per_eu(4, 4)))
void router_main(const float* __restrict__ x, const float* __restrict__ Wp,
                 const float* __restrict__ Wg, const float* __restrict__ lnw_g,
                 const float* __restrict__ lnb_g, const float* __restrict__ temp_g,
                 float* __restrict__ out_rw, float* __restrict__ out_disp,
                 float* __restrict__ ws_part)
{
    __shared__ __align__(16) float smem[SMEM_FLOATS];
    const int t  = threadIdx.x;
    const int tx = t & 15;           // h-lane (lane bits 0-3)
    const int ku = (t >> 4) & 3;     // private 4-k window (lane bits 4-5)
    const int wv = t >> 6;           // wave 0..15
    const int tb = wv & 7;           // token octet (8 tokens)
    const int hb = wv >> 3;          // h-half
    const int wrow = t >> 2;         // staging row 0..255
    const int wcol = (t & 3) << 2;   // staging col (floats)
    const int tok0 = blockIdx.x * TMB;

    // stage Wg once into persistent region [8224, 12320)
    *(float4*)&smem[WG_OFF + 4 * t] = *(const float4*)&Wg[4 * t];

    float acc[8][8];
    #pragma unroll
    for (int i = 0; i < 8; ++i)
        #pragma unroll
        for (int j = 0; j < 8; ++j) acc[i][j] = 0.f;

    float4 wpr, xr;
    auto ISSUE = [&](int k0) {
        wpr = *(const float4*)&Wp[(size_t)wrow * D + k0 + wcol];
        if (t < 256) xr = *(const float4*)&x[(size_t)(tok0 + wrow) * D + k0 + wcol];
    };
    ISSUE(0);

    const float* wbase = &smem[WP_OFF + (hb * 128 + tx) * LDK + ku * 4];
    const float* xbase = &smem[X_OFF + tb * 128 + ku * 4];

    for (int c = 0; c < NCH; ++c) {
        __syncthreads();                     // prior chunk's reads done
        *(float4*)&smem[WP_OFF + wrow * LDK + wcol] = wpr;
        if (t < 256) *(float4*)&smem[X_OFF + wrow * 16 + wcol] = xr;
        __syncthreads();
        if (c + 1 < NCH) ISSUE((c + 1) * BK);   // prefetch under compute

        float4 xa[8];
        #pragma unroll
        for (int i = 0; i < 8; ++i)
            xa[i] = *(const float4*)&xbase[i * 16];   // broadcast reads
        #pragma unroll
        for (int j = 0; j < 8; ++j) {
            const float4 wvv = *(const float4*)&wbase[j * 16 * LDK];  // 64-distinct b128
            #pragma unroll
            for (int i = 0; i < 8; ++i) {
                acc[i][j] = fmaf(xa[i].x, wvv.x, acc[i][j]);
                acc[i][j] = fmaf(xa[i].y, wvv.y, acc[i][j]);
                acc[i][j] = fmaf(xa[i].z, wvv.z, acc[i][j]);
                acc[i][j] = fmaf(xa[i].w, wvv.w, acc[i][j]);
            }
        }
    }

    // ---- k-window reduction: in-wave butterflies over lane bits 4,5 ----
    #pragma unroll
    for (int i = 0; i < 8; ++i)
        #pragma unroll
        for (int j = 0; j < 8; ++j) {
            acc[i][j] += __shfl_xor(acc[i][j], 16);
            acc[i][j] += __shfl_xor(acc[i][j], 32);
        }

    __syncthreads();                          // staging region now dead

    const float temp = fabsf(temp_g[0]) + 1e-6f;
    float lnw[16], lnb[16];
    if (t < 512) {
        #pragma unroll
        for (int j = 0; j < 16; ++j) {
            lnw[j] = lnw_g[(t & 15) + 16 * j];
            lnb[j] = lnb_g[(t & 15) + 16 * j];
        }
    }
    float mylb = 0.f, myz = 0.f;

    // ---------- two post passes over 32-token halves ----------
    #pragma unroll
    for (int pass = 0; pass < 2; ++pass) {
        // dump this half's proj into SB [32][257]
        if (ku == 0 && (tb >> 2) == pass) {
            const int rb = (tb & 3) * 8;
            #pragma unroll
            for (int i = 0; i < 8; ++i)
                #pragma unroll
                for (int j = 0; j < 8; ++j)
                    smem[SB_OFF + (rb + i) * SB_LDW + hb * 128 + tx + 16 * j] = acc[i][j];
        }
        if (pass == 0) {
            if (t < 16)  smem[LB_OFF + t] = 0.f;
            if (t == 16) smem[Z_OFF] = 0.f;
        }
        __syncthreads();

        if (t < 512) {
            const int ptx  = t & 15;
            const int tokl = t >> 4;                  // 0..31
            const int tok  = tok0 + pass * 32 + tokl;

            float pr[16];
            #pragma unroll
            for (int j = 0; j < 16; ++j)
                pr[j] = smem[SB_OFF + tokl * SB_LDW + ptx + 16 * j];

            // mean / variance over H (16-lane butterfly)
            float s = 0.f;
            #pragma unroll
            for (int j = 0; j < 16; ++j) s += pr[j];
            s += __shfl_xor(s, 1); s += __shfl_xor(s, 2);
            s += __shfl_xor(s, 4); s += __shfl_xor(s, 8);
            const float mu = s * (1.f / 256.f);
            float v = 0.f;
            #pragma unroll
            for (int j = 0; j < 16; ++j) { const float d = pr[j] - mu; v = fmaf(d, d, v); }
            v += __shfl_xor(v, 1); v += __shfl_xor(v, 2);
            v += __shfl_xor(v, 4); v += __shfl_xor(v, 8);
            const float rstd = 1.0f / sqrtf(v * (1.f / 256.f) + 1e-5f);

            float n[16];
            #pragma unroll
            for (int j = 0; j < 16; ++j)
                n[j] = fmaf((pr[j] - mu) * rstd, lnw[j], lnb[j]);

            float p[16];
            #pragma unroll
            for (int e = 0; e < 16; ++e) p[e] = 0.f;
            #pragma unroll
            for (int j = 0; j < 16; ++j) {
                const float nv = n[j];
                const int  h   = ptx + 16 * j;
                #pragma unroll
                for (int e = 0; e < 16; ++e)
                    p[e] = fmaf(nv, smem[WG_OFF + e * H + h], p[e]);
            }
            #pragma unroll
            for (int m = 1; m < 16; m <<= 1)
                #pragma unroll
                for (int e = 0; e < 16; ++e) p[e] += __shfl_xor(p[e], m);
            #pragma unroll
            for (int e = 0; e < 16; ++e) p[e] = p[e] / temp;

            if (ptx == 0) {
                #pragma unroll
                for (int e = 0; e < 16; ++e) myz = fmaf(p[e], p[e], myz);
            }

            // softmax (stable)
            float mx = p[0];
            #pragma unroll
            for (int e = 1; e < 16; ++e) mx = fmaxf(mx, p[e]);
            float w[16]; float sw = 0.f;
            #pragma unroll
            for (int e = 0; e < 16; ++e) { w[e] = expf(p[e] - mx); sw += w[e]; }
            #pragma unroll
            for (int e = 0; e < 16; ++e) w[e] = w[e] / sw;
            mylb += w[ptx];

            // top-2 (ties -> lower index)
            float w1 = -1.f; int i1 = 0; float w2 = -1.f; int i2 = 0;
            #pragma unroll
            for (int e = 0; e < 16; ++e) {
                const float we = w[e];
                if (we > w1)      { w2 = w1; i2 = i1; w1 = we; i1 = e; }
                else if (we > w2) { w2 = we; i2 = e; }
            }
            const float rs = 1.f / (w1 + w2 + 1e-6f);
            out_rw  [(size_t)tok * E + ptx] = w[ptx];
            out_disp[(size_t)tok * E + ptx] = (ptx == i1) ? w1 * rs : (ptx == i2 ? w2 * rs : 0.f);
        }
        __syncthreads();
    }

    // ---- loss partials: reduce 4 tokens/wave in-register, then LDS atomics ----
    if (t < 512) {
        mylb += __shfl_xor(mylb, 16); mylb += __shfl_xor(mylb, 32);
        myz  += __shfl_xor(myz, 16);  myz  += __shfl_xor(myz, 32);
        if ((t & 63) < 16) atomicAdd(&smem[LB_OFF + (t & 15)], mylb);
        if ((t & 63) == 0) atomicAdd(&smem[Z_OFF], myz);
    }
    __syncthreads();
    if (t < 16)  ws_part[blockIdx.x * WS_STRIDE + t]  = smem[LB_OFF + t];
    if (t == 16) ws_part[blockIdx.x * WS_STRIDE + 16] = smem[Z_OFF];
}

__global__ void router_final(const float* __restrict__ ws_part,
                             float* __restrict__ out_loss, int nblocks, int T)
{
    const int l = threadIdx.x;   // 64 threads
    float lb[16]; float z = 0.f;
    #pragma unroll
    for (int e = 0; e < 16; ++e) lb[e] = 0.f;
    for (int b = l; b < nblocks; b += 64) {
        #pragma unroll
        for (int e = 0; e < 16; ++e) lb[e] += ws_part[b * WS_STRIDE + e];
        z += ws_part[b * WS_STRIDE + 16];
    }
    #pragma unroll
    for (int m = 1; m < 64; m <<= 1) {
        #pragma unroll
        for (int e = 0; e < 16; ++e) lb[e] += __shfl_xor(lb[e], m);
        z += __shfl_xor(z, m);
    }
    if (l == 0) {
        const float zloss = z / (float)(T * 16);
        const float ideal = 1.f / 16.f;
        float lbl = 0.f;
        #pragma unroll
        for (int e = 0; e < 16; ++e) {
            const float a = lb[e] / (float)T;
            lbl += ideal * (logf(ideal) - logf(a));
        }
        lbl *= (1.f / 16.f);
        out_loss[0] = 0.005f * zloss + 0.005f * lbl;
    }
}

extern "C" void kernel_launch(void* const* d_in, const int* in_sizes, int n_in,
                              void* d_out, int out_size, void* d_ws, size_t ws_size,
                              hipStream_t stream)
{
    const float* x    = (const float*)d_in[0];
    const float* Wp   = (const float*)d_in[1];
    const float* Wg   = (const float*)d_in[2];
    const float* lnw  = (const float*)d_in[3];
    const float* lnb  = (const float*)d_in[4];
    const float* temp = (const float*)d_in[5];
    const int T = in_sizes[0] / D;           // 16384
    float* out      = (float*)d_out;
    float* out_rw   = out;
    float* out_disp = out + (size_t)T * E;
    float* out_loss = out + (size_t)2 * T * E;
    float* ws_part  = (float*)d_ws;
    const int nblocks = T / TMB;             // 256

    hipLaunchKernelGGL(router_main, dim3(nblocks), dim3(THREADS), 0, stream,
                       x, Wp, Wg, lnw, lnb, temp, out_rw, out_disp, ws_part);
    hipLaunchKernelGGL(router_final, dim3(1), dim3(64), 0, stream,
                       ws_part, out_loss, nblocks, T);
}